// Round 5
// baseline (332.699 us; speedup 1.0000x reference)
//
#include <hip/hip_runtime.h>

#define G 5000
#define K 256
#define BATCH 16
#define HID 64
#define STEPS 10
#define NBLK 256        // 1 block/CU at __launch_bounds__(1024,4): co-resident
#define NTHR 1024
#define GP 20           // genes per block: 250 blocks cover 5000 exactly
#define NCHUNK 250      // chunks actually written in phase 1

// ---------------------------------------------------------------------------
// Hand-rolled grid barrier, poison-tolerant (flags start at 0xAA.. < 1).
// Arrival: block stores flags[blk]=gen (release, device scope).
// Block 0 wave 0 scans all flags, then publishes `release`=gen; other blocks
// poll the single release word with fixed s_sleep(4) (no backoff escalation —
// the thing that killed cg::grid.sync at ~55 us each).
// ---------------------------------------------------------------------------
__device__ __forceinline__ void grid_barrier(int* __restrict__ flags,
                                             int* __restrict__ release,
                                             int gen, int blk, int tid) {
    __syncthreads();
    if (tid == 0) {
        __threadfence();   // release this block's global writes
        __hip_atomic_store(&flags[blk], gen, __ATOMIC_RELEASE,
                           __HIP_MEMORY_SCOPE_AGENT);
    }
    if (blk == 0) {
        if (tid < 64) {
#pragma unroll
            for (int i = 0; i < 4; ++i) {
                while (__hip_atomic_load(&flags[tid + 64 * i], __ATOMIC_ACQUIRE,
                                         __HIP_MEMORY_SCOPE_AGENT) < gen)
                    __builtin_amdgcn_s_sleep(1);
            }
        }
        __syncthreads();
        if (tid == 0) {
            __threadfence();
            __hip_atomic_store(release, gen, __ATOMIC_RELEASE,
                               __HIP_MEMORY_SCOPE_AGENT);
        }
    } else if (tid == 0) {
        while (__hip_atomic_load(release, __ATOMIC_ACQUIRE,
                                 __HIP_MEMORY_SCOPE_AGENT) < gen)
            __builtin_amdgcn_s_sleep(4);
    }
    __syncthreads();
    __threadfence();       // acquire side: subsequent reads see all blocks' writes
}

// ---------------------------------------------------------------------------
// Single regular kernel, 3 phases:
//  P1 (all 256 blocks): partial max-pool, 20 genes/block
//  P2 (blocks 0..15):   APPNP chain, A register-stationary (round-3 structure)
//  P3 (blocks 0..249):  z_gene @ M^T + MLP, 20 genes/block
// All FMA chains keep round-3 order -> bitwise-identical output.
// ---------------------------------------------------------------------------
__global__ __launch_bounds__(NTHR, 4)
void fused_all(const float* __restrict__ ctl,
               const float* __restrict__ tgt,
               const int* __restrict__ cell_idx,
               const float* __restrict__ M,
               const float* __restrict__ A,
               const float* __restrict__ W1,
               const float* __restrict__ b1,
               const float* __restrict__ cell_emb,
               const float* __restrict__ W2,
               const float* __restrict__ b2,
               float* __restrict__ out,
               float* __restrict__ partials,   // NCHUNK*16*256
               float* __restrict__ Zfin,       // 16*256
               float* __restrict__ ce_dot,     // 16
               int* __restrict__ flags,        // 256 (poisoned = negative, ok)
               int* __restrict__ release) {    // 1
    __shared__ float  tl[GP][BATCH];     // P1: 1.25 KB
    __shared__ float  Sm[K];             // P2
    __shared__ float  red[4][K];         // P2
    __shared__ float  ce_red[HID];       // P2
    __shared__ float4 zb[2][K / 4];      // P2: double-buffered Z row
    __shared__ float4 zl[BATCH * (K/4)]; // P3: 16 KB
    __shared__ float4 wpack[HID];        // P3
    __shared__ float  w2l[HID];          // P3
    __shared__ float  cel[BATCH];        // P3

    const int blk = blockIdx.x;
    const int tid = threadIdx.x;
    const int g0  = blk * GP;

    // ================= Phase 1: max-pool partials (20 genes/block) ==========
    if (g0 < G) {
        if (tid < GP * BATCH) {          // stage t[b, g0..g0+19] in LDS
            int gi = tid >> 4, b = tid & 15;
            tl[gi][b] = tgt[b * G + g0 + gi];
        }
        __syncthreads();
        const int k  = tid & 255;
        const int bh = tid >> 8;         // 0..3, wave-uniform
        float mx0 = 0.f, mx1 = 0.f, mx2 = 0.f, mx3 = 0.f;
#pragma unroll
        for (int gi = 0; gi < GP; ++gi) {
            float mg = M[(size_t)(g0 + gi) * K + k];   // coalesced across k
            mx0 = fmaxf(mx0, tl[gi][bh*4 + 0] * mg);   // LDS broadcast
            mx1 = fmaxf(mx1, tl[gi][bh*4 + 1] * mg);
            mx2 = fmaxf(mx2, tl[gi][bh*4 + 2] * mg);
            mx3 = fmaxf(mx3, tl[gi][bh*4 + 3] * mg);
        }
        partials[((size_t)blk * BATCH + bh*4 + 0) * K + k] = mx0;
        partials[((size_t)blk * BATCH + bh*4 + 1) * K + k] = mx1;
        partials[((size_t)blk * BATCH + bh*4 + 2) * K + k] = mx2;
        partials[((size_t)blk * BATCH + bh*4 + 3) * K + k] = mx3;
    }
    grid_barrier(flags, release, 1, blk, tid);

    // ================= Phase 2: APPNP (blocks 0..15) ========================
    if (blk < BATCH) {
        const int b  = blk;
        const int k  = tid & 255;
        const int jc = tid >> 8;         // 0..3, wave-uniform
        const int j0 = jc * 64;

        float Areg[64];                  // A column-slice stationary in VGPRs
#pragma unroll
        for (int jj = 0; jj < 64; ++jj)
            Areg[jj] = A[(size_t)(j0 + jj) * K + k];

        {                                // reduce the 250 chunk slots
            float m = 0.f;
            const int c1 = min(NCHUNK, j0 + 64);
            for (int c = j0; c < c1; ++c)
                m = fmaxf(m, partials[((size_t)c * BATCH + b) * K + k]);
            red[jc][k] = m;
        }
        if (tid < HID)
            ce_red[tid] = cell_emb[cell_idx[b] * HID + tid] * W2[tid];
        __syncthreads();
        if (jc == 0) {
            float s = fmaxf(fmaxf(red[0][k], red[1][k]),
                            fmaxf(red[2][k], red[3][k]));
            Sm[k] = s;
            ((float*)zb)[k] = s;         // zb[0] = Z0 = S
        }
        if (tid == 0) {
            float s = b2[0];
            for (int h = 0; h < HID; ++h) s += ce_red[h];
            ce_dot[b] = s;
        }
        __syncthreads();

        for (int s = 0; s < STEPS; ++s) {
            const float4* cur4 = zb[s & 1] + (j0 >> 2);
            float*        nxt  = (float*)zb[(s + 1) & 1];
            float acc = 0.f;
#pragma unroll
            for (int q = 0; q < 16; ++q) {
                float4 c4 = cur4[q];               // LDS broadcast, b128
                acc = fmaf(c4.x, Areg[4*q + 0], acc);
                acc = fmaf(c4.y, Areg[4*q + 1], acc);
                acc = fmaf(c4.z, Areg[4*q + 2], acc);
                acc = fmaf(c4.w, Areg[4*q + 3], acc);
            }
            red[jc][k] = acc;
            __syncthreads();
            if (jc == 0)
                nxt[k] = 0.9f * (red[0][k] + red[1][k] + red[2][k] + red[3][k])
                       + 0.1f * Sm[k];
            __syncthreads();
        }
        if (jc == 0) Zfin[b * K + k] = ((float*)zb)[k];  // 10 even steps -> zb[0]
    }
    grid_barrier(flags, release, 2, blk, tid);

    // ================= Phase 3: final (blocks 0..249, 20 genes each) ========
    if (g0 < G) {
        const float4* Z4 = (const float4*)Zfin;
        zl[tid & (BATCH * (K/4) - 1)] = Z4[tid & (BATCH * (K/4) - 1)]; // 1024 = exact
        if (tid < HID) {
            wpack[tid] = make_float4(W1[tid], W1[HID + tid], W1[2*HID + tid], b1[tid]);
            w2l[tid] = W2[tid];
        }
        if (tid < BATCH) cel[tid] = ce_dot[tid];
        __syncthreads();

        const int gl = tid & 63;         // gene slot (use 0..19)
        const int b  = tid >> 6;         // 0..15, wave-uniform
        const int g  = g0 + gl;
        if (gl < GP && g < G) {
            float acc = 0.f;
            const float4* M4   = (const float4*)(M + (size_t)g * K);
            const float4* zrow = &zl[b * (K/4)];
#pragma unroll 8
            for (int k4 = 0; k4 < K/4; ++k4) {
                float4 m4 = M4[k4];
                float4 z4 = zrow[k4];    // wave-uniform LDS broadcast
                acc = fmaf(m4.x, z4.x, acc);
                acc = fmaf(m4.y, z4.y, acc);
                acc = fmaf(m4.z, z4.z, acc);
                acc = fmaf(m4.w, z4.w, acc);
            }
            float cv = ctl[b * G + g];
            float tv = tgt[b * G + g];
            float y  = cel[b];
#pragma unroll 4
            for (int h = 0; h < HID; ++h) {
                float4 w = wpack[h];
                float pre = fmaf(cv, w.x, w.w);
                pre = fmaf(tv, w.y, pre);
                pre = fmaf(acc, w.z, pre);
                pre = fmaxf(pre, 0.f);
                y = fmaf(pre, w2l[h], y);
            }
            out[b * G + g] = y;
        }
    }
}

// ---------------------------------------------------------------------------
extern "C" void kernel_launch(void* const* d_in, const int* in_sizes, int n_in,
                              void* d_out, int out_size, void* d_ws, size_t ws_size,
                              hipStream_t stream) {
    const float* ctl      = (const float*)d_in[0];
    const float* tgt      = (const float*)d_in[1];
    const int*   cell_idx = (const int*)d_in[2];
    // d_in[3] = drug_fp (unused by the reference output)
    const float* M        = (const float*)d_in[4];
    const float* A        = (const float*)d_in[5];
    const float* W1       = (const float*)d_in[6];
    const float* b1       = (const float*)d_in[7];
    const float* cell_emb = (const float*)d_in[8];
    const float* W2       = (const float*)d_in[9];
    const float* b2       = (const float*)d_in[10];
    float* out = (float*)d_out;

    float* partials = (float*)d_ws;                          // 250*16*256 f32
    float* Zfin     = partials + (size_t)NCHUNK * BATCH * K;
    float* ce       = Zfin + BATCH * K;
    int*   flags    = (int*)(ce + BATCH);                    // poison-tolerant
    int*   release  = flags + NBLK;

    fused_all<<<NBLK, NTHR, 0, stream>>>(ctl, tgt, cell_idx, M, A, W1, b1,
                                         cell_emb, W2, b2, out,
                                         partials, Zfin, ce, flags, release);
}

// Round 6
// 116.277 us; speedup vs baseline: 2.8613x; 2.8613x over previous
//
#include <hip/hip_runtime.h>

#define G 5000
#define K 256
#define BATCH 16
#define HID 64
#define STEPS 10
#define NC 125          // gene chunks: 125 * 40 == 5000 exactly
#define GPER 40

// ---------------------------------------------------------------------------
// Kernel A: partial max-pool. 250 blocks = 125 chunks x 2 batch-groups(8).
// partials[c][b][k] = max_{g in chunk c} t[b,g] * M[g,k]
// t,M >= 0, so 0 is a valid identity for the running max.
// Side job: warm A into L3 (each block touches a 1KB slice) so the appnp
// kernel's 16 blocks x 256KB A-preload hits Infinity Cache, not HBM.
// ---------------------------------------------------------------------------
__global__ void maxpool_kernel(const float* __restrict__ t,
                               const float* __restrict__ M,
                               const float* __restrict__ A,
                               float* __restrict__ partials,
                               float* __restrict__ awarm) {
    __shared__ float tl[GPER][8];        // t values for this chunk x 8 batches
    const int c  = blockIdx.x >> 1;      // chunk 0..124
    const int bg = blockIdx.x & 1;       // batch group 0..1
    const int b0 = bg * 8;
    const int k  = threadIdx.x;          // 0..255
    const int g0 = c * GPER;

    // ---- A-warm: 64 lanes pull one float4 each (1KB/block, ~full A overall)
    float4 aw = make_float4(0.f, 0.f, 0.f, 0.f);
    if (k < 64)
        aw = ((const float4*)A)[((size_t)blockIdx.x * 64 + k) & 16383];

    // ---- stage t[b0..b0+7, g0..g0+39] into LDS
    for (int i = k; i < GPER * 8; i += 256) {
        int gi = i >> 3, b = i & 7;
        tl[gi][b] = t[(b0 + b) * G + g0 + gi];
    }
    __syncthreads();

    float mx[8];
#pragma unroll
    for (int b = 0; b < 8; ++b) mx[b] = 0.f;

#pragma unroll 4
    for (int gi = 0; gi < GPER; ++gi) {
        float mg = M[(size_t)(g0 + gi) * K + k];   // coalesced across k
#pragma unroll
        for (int b = 0; b < 8; ++b)
            mx[b] = fmaxf(mx[b], tl[gi][b] * mg);  // LDS broadcast
    }
#pragma unroll
    for (int b = 0; b < 8; ++b)
        partials[((size_t)c * BATCH + b0 + b) * K + k] = mx[b];

    // keep the A-warm loads alive (64 garbage floats in ws, raced by blocks)
    if (k < 64) awarm[k] = aw.x + aw.y + aw.z + aw.w;
}

// ---------------------------------------------------------------------------
// Kernel B: full APPNP chain, ONE dispatch, A-STATIONARY IN REGISTERS
// (round-3 structure — standalone kernel so Areg[64] stays in VGPRs; the
// fused variants spilled it to scratch, R4/R5 post-mortem). One block per
// batch row; thread (k, jc) owns A[jc*64..+63, k] in 64 VGPRs.
// ---------------------------------------------------------------------------
__global__ __launch_bounds__(1024, 4)
void appnp_fused(const float* __restrict__ partials,
                 const float* __restrict__ A,
                 const int* __restrict__ cell_idx,
                 const float* __restrict__ cell_emb,
                 const float* __restrict__ W2,
                 const float* __restrict__ b2,
                 float* __restrict__ Zfin,
                 float* __restrict__ ce_dot) {
    __shared__ float4 zb[2][K / 4];      // double-buffered Z row
    __shared__ float  Sm[K];
    __shared__ float  red[4][K];
    __shared__ float  ce_red[HID];

    const int b  = blockIdx.x;
    const int t  = threadIdx.x;
    const int k  = t & 255;
    const int jc = t >> 8;               // 0..3, wave-uniform
    const int j0 = jc * 64;

    // ---- preload this thread's A column-slice into registers (L3-warm) ----
    float Areg[64];
#pragma unroll
    for (int jj = 0; jj < 64; ++jj)
        Areg[jj] = A[(size_t)(j0 + jj) * K + k];     // coalesced across k

    // ---- reduce partials over the 125 chunks (4-way split over jc) ----
    {
        int c0 = jc * 32, c1 = min(NC, c0 + 32);
        float m = 0.f;
        for (int c = c0; c < c1; ++c)
            m = fmaxf(m, partials[((size_t)c * BATCH + b) * K + k]);
        red[jc][k] = m;
    }
    if (t < HID) {
        int ci = cell_idx[b];
        ce_red[t] = cell_emb[ci * HID + t] * W2[t];
    }
    __syncthreads();
    if (jc == 0) {
        float s = fmaxf(fmaxf(red[0][k], red[1][k]), fmaxf(red[2][k], red[3][k]));
        Sm[k] = s;
        ((float*)zb)[k] = s;             // zb[0] = Z0
    }
    if (t == 0) {
        float s = b2[0];
        for (int h = 0; h < HID; ++h) s += ce_red[h];
        ce_dot[b] = s;
    }
    __syncthreads();

    // ---- 10 propagation steps, LDS+register only ----
    for (int s = 0; s < STEPS; ++s) {
        const float4* cur4 = zb[s & 1] + (j0 >> 2);
        float*        nxt  = (float*)zb[(s + 1) & 1];
        float acc = 0.f;
#pragma unroll
        for (int q = 0; q < 16; ++q) {
            float4 c4 = cur4[q];                     // wave-uniform LDS broadcast
            acc = fmaf(c4.x, Areg[4 * q + 0], acc);
            acc = fmaf(c4.y, Areg[4 * q + 1], acc);
            acc = fmaf(c4.z, Areg[4 * q + 2], acc);
            acc = fmaf(c4.w, Areg[4 * q + 3], acc);
        }
        red[jc][k] = acc;
        __syncthreads();
        if (jc == 0)
            nxt[k] = 0.9f * (red[0][k] + red[1][k] + red[2][k] + red[3][k])
                   + 0.1f * Sm[k];
        __syncthreads();
    }
    // after 10 (even) steps the result sits in zb[0]
    if (jc == 0) Zfin[b * K + k] = ((float*)zb)[k];
}

// ---------------------------------------------------------------------------
// Kernel C: z_gene = Z @ M^T fused with the per-element MLP (unchanged).
// ---------------------------------------------------------------------------
__global__ void final_kernel(const float* __restrict__ ctl,
                             const float* __restrict__ t_in,
                             const float* __restrict__ Z,
                             const float* __restrict__ M,
                             const float* __restrict__ W1,
                             const float* __restrict__ b1,
                             const float* __restrict__ W2,
                             const float* __restrict__ ce_dot,
                             float* __restrict__ out) {
    __shared__ float4 zl[BATCH * (K / 4)];   // 16 KB, Z rows as float4
    __shared__ float4 wpack[HID];            // (W1row0, W1row1, W1row2, b1)
    __shared__ float  w2l[HID];
    __shared__ float  cel[BATCH];

    const int t = threadIdx.x;
    const float4* Z4 = (const float4*)Z;
    for (int i = t; i < BATCH * (K / 4); i += 256) zl[i] = Z4[i];
    if (t < HID) {
        wpack[t] = make_float4(W1[t], W1[HID + t], W1[2 * HID + t], b1[t]);
        w2l[t] = W2[t];
    }
    if (t < BATCH) cel[t] = ce_dot[t];
    __syncthreads();

    const int gl = t & 63;
    const int bg = t >> 6;             // wave-uniform -> LDS broadcasts below
    const int g = blockIdx.x * 64 + gl;
    if (g >= G) return;

    float acc[4] = {0.f, 0.f, 0.f, 0.f};
    const float4* M4 = (const float4*)(M + (size_t)g * K);
#pragma unroll 4
    for (int k4 = 0; k4 < K / 4; ++k4) {
        float4 m4 = M4[k4];
#pragma unroll
        for (int i = 0; i < 4; ++i) {
            float4 z4 = zl[(bg * 4 + i) * (K / 4) + k4];   // broadcast read
            acc[i] = fmaf(m4.x, z4.x, acc[i]);
            acc[i] = fmaf(m4.y, z4.y, acc[i]);
            acc[i] = fmaf(m4.z, z4.z, acc[i]);
            acc[i] = fmaf(m4.w, z4.w, acc[i]);
        }
    }

    float cv[4], tv[4], y[4];
#pragma unroll
    for (int i = 0; i < 4; ++i) {
        int b = bg * 4 + i;
        cv[i] = ctl[b * G + g];        // coalesced across gl
        tv[i] = t_in[b * G + g];
        y[i] = cel[b];
    }
#pragma unroll 4
    for (int h = 0; h < HID; ++h) {
        float4 w = wpack[h];           // broadcast
        float w2h = w2l[h];
#pragma unroll
        for (int i = 0; i < 4; ++i) {
            float pre = w.w;
            pre = fmaf(cv[i], w.x, pre);
            pre = fmaf(tv[i], w.y, pre);
            pre = fmaf(acc[i], w.z, pre);
            pre = fmaxf(pre, 0.f);
            y[i] = fmaf(pre, w2h, y[i]);
        }
    }
#pragma unroll
    for (int i = 0; i < 4; ++i)
        out[(bg * 4 + i) * G + g] = y[i];
}

// ---------------------------------------------------------------------------
extern "C" void kernel_launch(void* const* d_in, const int* in_sizes, int n_in,
                              void* d_out, int out_size, void* d_ws, size_t ws_size,
                              hipStream_t stream) {
    const float* ctl      = (const float*)d_in[0];
    const float* tgt      = (const float*)d_in[1];
    const int*   cell_idx = (const int*)d_in[2];
    // d_in[3] = drug_fp (unused by the reference output)
    const float* M        = (const float*)d_in[4];
    const float* A        = (const float*)d_in[5];
    const float* W1       = (const float*)d_in[6];
    const float* b1       = (const float*)d_in[7];
    const float* cell_emb = (const float*)d_in[8];
    const float* W2       = (const float*)d_in[9];
    const float* b2       = (const float*)d_in[10];
    float* out = (float*)d_out;

    float* partials = (float*)d_ws;                     // 125*16*256 f32 (2 MB)
    float* Zfin  = partials + (size_t)NC * BATCH * K;   // 16*256
    float* ce    = Zfin + BATCH * K;                    // 16
    float* awarm = ce + BATCH;                          // 64 (garbage dump)

    maxpool_kernel<<<NC * 2, 256, 0, stream>>>(tgt, M, A, partials, awarm);
    appnp_fused<<<BATCH, 1024, 0, stream>>>(partials, A, cell_idx, cell_emb,
                                            W2, b2, Zfin, ce);
    final_kernel<<<(G + 63) / 64, 256, 0, stream>>>(ctl, tgt, Zfin, M, W1, b1,
                                                    W2, ce, out);
}